// Round 7
// baseline (1145.976 us; speedup 1.0000x reference)
//
#include <hip/hip_runtime.h>
#include <stdint.h>

#define HH 224
#define WW 224
#define BB 4
#define PP 7          // seams per direction
#define SEG 28
#define BW 5
#define MM 11         // 2*BW+1
#define NBLK 784u     // 7*28*4 vote blocks (co-resident: 4 blk/CU * 256 CU = 1024 cap)

#define POS_INF_I 0x7F800000

typedef const __attribute__((address_space(1))) unsigned int* gas_ptr;
typedef __attribute__((address_space(3))) unsigned int* las_ptr;

// map-compose for 11-entry 4-bit-nibble maps packed in u64:  H[i] = F[G[i]]
__device__ inline unsigned long long mcompose(unsigned long long F, unsigned long long G) {
    unsigned long long H = 0ull;
#pragma unroll
    for (int i = 0; i < 11; ++i) {
        unsigned g = (unsigned)(G >> (4 * i)) & 15u;
        H |= ((F >> (4 * g)) & 15ull) << (4 * i);
    }
    return H;
}

// ---------------------------------------------------------------------------
// DP kernel (body unchanged from R4 — verified absmax 0). Block 0 additionally
// zeroes the grid-barrier slots in ws (visible to mega_kernel via stream order).
// ---------------------------------------------------------------------------
__global__ __launch_bounds__(64) void dp_kernel(const float* __restrict__ grad,
                                                int* __restrict__ coords_v,
                                                int* __restrict__ coords_h,
                                                unsigned* __restrict__ bars) {
    __shared__ __align__(16) float gseg[225 * 16];

    const int tid = threadIdx.x;
    const int l   = tid & 15;
    const int sid = blockIdx.x;
    if (sid == 0 && tid < 16) bars[tid * 16] = 0u;   // 5 slots used, 64B apart

    const int p   = sid % PP;
    const int dir = (sid / PP) & 1;
    const int b   = sid / (2 * PP);
    const int base = SEG * (p + 1);
    const float* gb = grad + b * (HH * WW);

    {
        const int r  = tid >> 4;
        const int m  = tid & 15;
        const int sS = (dir == 0) ? WW : 1;
        const int sM = (dir == 0) ? 1  : WW;
        const float* src = gb + r * sS + (base - BW + m) * sM;
        const long stepBytes = (long)(4 * sS) * 4;
#pragma unroll 8
        for (int c = 0; c < 56; ++c) {
            __builtin_amdgcn_global_load_lds((gas_ptr)(const void*)src,
                                             (las_ptr)(void*)(&gseg[c * 64]), 4, 0, 0);
            src = (const float*)((const char*)src + stepBytes);
        }
    }
    __syncthreads();

    const float lane_add = (l < MM) ? 0.0f : __int_as_float(POS_INF_I);
    const float* gp = &gseg[l];

    unsigned wreg[16] = {};

#define DP_STEP(gval, ownb, jj_c)                                                       \
    {                                                                                   \
        float v1 = cost;                                                                \
        float v0 = __int_as_float(__builtin_amdgcn_update_dpp(                          \
            POS_INF_I, __float_as_int(cost), 0x111, 0xf, 0xf, false));                  \
        float v2 = __int_as_float(__builtin_amdgcn_update_dpp(                          \
            POS_INF_I, __float_as_int(cost), 0x101, 0xf, 0xf, false));                  \
        bool a01 = (v0 <= v1), a02 = (v0 <= v2), a12 = (v1 <= v2);                      \
        bool aa  = a01 && a02;                                                          \
        unsigned long long A   = __ballot(aa);                                          \
        unsigned long long C12 = __ballot(a12);                                         \
        unsigned long long B0 = ~A & C12;                                               \
        unsigned long long B1 = ~A & ~C12;                                              \
        float mv = aa ? v0 : (a12 ? v1 : v2);                                           \
        cost = mv - (gval) + lane_add;                                                  \
        unsigned wv = (unsigned)(B0 & 0x7FFull) | ((unsigned)(B1 & 0x7FFull) << 11);    \
        wreg[(jj_c)] = (ownb) ? wv : wreg[(jj_c)];                                      \
    }

    float cost = -gp[0] + lane_add;
    float buf[16], c0[16];
#pragma unroll
    for (int k = 0; k < 16; ++k) buf[k] = gp[(1 + k) * 16];
    for (int t = 0; t < 13; ++t) {
        const bool own = (tid == t);
#pragma unroll
        for (int k = 0; k < 16; ++k) c0[k] = buf[k];
#pragma unroll
        for (int k = 0; k < 16; ++k) buf[k] = gp[(16 * (t + 1) + 1 + k) * 16];
#pragma unroll
        for (int k = 0; k < 16; ++k) DP_STEP(c0[k], own, k)
    }
    {
        const bool own = (tid == 13);
#pragma unroll
        for (int k = 0; k < 15; ++k) DP_STEP(buf[k], own, k)
    }
#undef DP_STEP

    float bc = cost;
    int   bi = l;
#pragma unroll
    for (int mask = 1; mask < 16; mask <<= 1) {
        float oc = __shfl_xor(bc, mask, 16);
        int   oi = __shfl_xor(bi, mask, 16);
        if (oc < bc || (oc == bc && oi < bi)) { bc = oc; bi = oi; }
    }
    const int idx_last = bi;

    const int mcnt = (l < 13) ? 16 : ((l == 13) ? 15 : 0);
    const unsigned long long IDMAP = 0xA9876543210ull;
    unsigned long long L = IDMAP;
#pragma unroll
    for (int jj = 15; jj >= 0; --jj) {
        if (jj < mcnt) {
            unsigned ww = wreg[jj];
            unsigned long long M = 0ull;
#pragma unroll
            for (int i = 0; i < MM; ++i) {
                unsigned sel = ((ww >> i) & 1u) + 2u * ((ww >> (11 + i)) & 1u);
                M |= ((unsigned long long)(i + (int)sel - 1)) << (4 * i);
            }
            L = mcompose(M, L);
        }
    }
    unsigned long long I = L;
#pragma unroll
    for (int d = 1; d < 16; d <<= 1) {
        unsigned long long O = __shfl_down(I, d, 16);
        if (l + d < 16) I = mcompose(I, O);
    }
    unsigned long long R = __shfl_down(I, 1, 16);
    if (l == 15) R = IDMAP;

    int* cout = (dir == 0) ? coords_v : coords_h;
    if (tid == 15) cout[(b * HH + 223) * PP + p] = base + idx_last - BW;
    if (tid < 16) {
        unsigned v = (unsigned)(R >> (4 * idx_last)) & 15u;
#pragma unroll
        for (int jj = 15; jj >= 0; --jj) {
            if (jj < mcnt) {
                unsigned ww = wreg[jj];
                unsigned sel = ((ww >> v) & 1u) + 2u * ((ww >> (11 + v)) & 1u);
                v = v + sel - 1u;
                cout[(b * HH + (16 * l + jj)) * PP + p] = base + (int)v - BW;
            }
        }
    }
}

// ---------------------------------------------------------------------------
// Grid barrier: monotone counting, agent scope. Slots pre-zeroed by dp_kernel.
// All 784 blocks are co-resident (4 blk/CU via __launch_bounds__(256,4);
// LDS 17.4 KB -> 9 blk/CU by LDS; waves 16/CU <= 32) => no deadlock.
// ---------------------------------------------------------------------------
__device__ inline void grid_barrier(unsigned* slot, int t) {
    __syncthreads();
    __threadfence();                 // release our stores agent-wide
    if (t == 0) {
        __hip_atomic_fetch_add(slot, 1u, __ATOMIC_ACQ_REL, __HIP_MEMORY_SCOPE_AGENT);
        while (__hip_atomic_load(slot, __ATOMIC_ACQUIRE, __HIP_MEMORY_SCOPE_AGENT) < NBLK)
            __builtin_amdgcn_s_sleep(2);
    }
    __syncthreads();
    __threadfence();                 // acquire: see other blocks' stores
}

// R4-proven vote body: 7x7 Chebyshev-weighted histogram, byte-packed LDS bins,
// OOB -> sentinel bin 64, argmax first-max.
__device__ inline int vote_px(const unsigned char* __restrict__ img,
                              int gx, int gy, unsigned* bins, int t) {
#pragma unroll
    for (int c = 0; c < 17; ++c) bins[c * 256 + t] = 0u;
#pragma unroll
    for (int dy = -3; dy <= 3; ++dy) {
        int yy = gy + dy;
        bool oky = (unsigned)yy < (unsigned)HH;
        int yc = min(max(yy, 0), HH - 1);
#pragma unroll
        for (int dx = -3; dx <= 3; ++dx) {
            int xx = gx + dx;
            bool ok = oky && ((unsigned)xx < (unsigned)WW);
            int xc = min(max(xx, 0), WW - 1);
            int lab = img[yc * WW + xc];
            lab = ok ? lab : 64;
            const int ady = dy < 0 ? -dy : dy;
            const int adx = dx < 0 ? -dx : dx;
            const int d = ady > adx ? ady : adx;
            const unsigned wgt = (d <= 1) ? 3u : (unsigned)(4 - d);
            atomicAdd(&bins[(lab >> 2) * 256 + t], wgt << ((lab & 3) * 8));
        }
    }
    int best_s = -1, best_k = 0;
#pragma unroll
    for (int c = 0; c < 16; ++c) {
        unsigned wd = bins[c * 256 + t];
#pragma unroll
        for (int q = 0; q < 4; ++q) {
            int s = (int)((wd >> (q * 8)) & 255u);
            if (s > best_s) { best_s = s; best_k = c * 4 + q; }
        }
    }
    return best_k;
}

// ---------------------------------------------------------------------------
// Mega kernel: initial labels + 5 vote iterations, grid-barrier between phases.
// Grid (7,28,4) x (32,8) = 784 blocks. Zero redundant work.
// ---------------------------------------------------------------------------
__global__ __launch_bounds__(256, 4) void mega_kernel(const int* __restrict__ cv,
                                                      const int* __restrict__ ch,
                                                      unsigned char* __restrict__ bufA,
                                                      unsigned char* __restrict__ bufB,
                                                      unsigned* __restrict__ bars,
                                                      int* __restrict__ out) {
    __shared__ unsigned bins[17 * 256];
    const int tx = threadIdx.x, ty = threadIdx.y;
    const int t  = ty * 32 + tx;
    const int b  = blockIdx.z;
    const int gx = blockIdx.x * 32 + tx;
    const int gy = blockIdx.y * 8 + ty;
    const int o  = (b * HH + gy) * WW + gx;

    // phase 0: initial label (analytic, own pixel only)
    {
        const int* cvp = cv + (b * HH + gy) * PP;
        const int* chp = ch + (b * WW + gx) * PP;
        int v = 0, h = 0;
#pragma unroll
        for (int q = 0; q < PP; ++q) { v += (cvp[q] <= gx); h += (chp[q] <= gy); }
        bufA[o] = (unsigned char)(v + 8 * h);
    }
    grid_barrier(&bars[0], t);

    // iterations 1..5: odd reads A writes B, even reads B writes A; 5th -> out
    for (int it = 1; it <= 5; ++it) {
        const unsigned char* src = (it & 1) ? bufA : bufB;
        unsigned char*       dst = (it & 1) ? bufB : bufA;
        int bk = vote_px(src + b * (HH * WW), gx, gy, bins, t);
        if (it < 5) {
            dst[o] = (unsigned char)bk;
            grid_barrier(&bars[it * 16], t);
        } else {
            out[o] = bk;
        }
    }
}

// ---------------------------------------------------------------------------
extern "C" void kernel_launch(void* const* d_in, const int* in_sizes, int n_in,
                              void* d_out, int out_size, void* d_ws, size_t ws_size,
                              hipStream_t stream) {
    const float* grad = (const float*)d_in[0];
    int* out = (int*)d_out;
    char* ws = (char*)d_ws;

    int* cv = (int*)(ws);                                 // 25088 B
    int* ch = (int*)(ws + 25088);                         // 25088 B
    unsigned char* bufA = (unsigned char*)(ws + 50176);   // 200704 B
    unsigned char* bufB = (unsigned char*)(ws + 250880);  // 200704 B
    unsigned* bars = (unsigned*)(ws + 451584);            // 16 slots * 64 B

    dp_kernel<<<56, 64, 0, stream>>>(grad, cv, ch, bars);

    dim3 grid(WW / 32, HH / 8, BB), blk(32, 8, 1);
    mega_kernel<<<grid, blk, 0, stream>>>(cv, ch, bufA, bufB, bars, out);
}

// Round 8
// 123.422 us; speedup vs baseline: 9.2850x; 9.2850x over previous
//
#include <hip/hip_runtime.h>
#include <stdint.h>

#define HH 224
#define WW 224
#define BB 4
#define PP 7          // seams per direction
#define SEG 28
#define BW 5
#define MM 11         // 2*BW+1

#define POS_INF_I 0x7F800000

typedef const __attribute__((address_space(1))) unsigned int* gas_ptr;
typedef __attribute__((address_space(3))) unsigned int* las_ptr;

// map-compose for 11-entry 4-bit-nibble maps packed in u64:  H[i] = F[G[i]]
__device__ inline unsigned long long mcompose(unsigned long long F, unsigned long long G) {
    unsigned long long H = 0ull;
#pragma unroll
    for (int i = 0; i < 11; ++i) {
        unsigned g = (unsigned)(G >> (4 * i)) & 15u;
        H |= ((F >> (4 * g)) & 15ull) << (4 * i);
    }
    return H;
}

// ---------------------------------------------------------------------------
// DP kernel (unchanged from R4 — verified absmax 0, ~6 us)
// ---------------------------------------------------------------------------
__global__ __launch_bounds__(64) void dp_kernel(const float* __restrict__ grad,
                                                int* __restrict__ coords_v,
                                                int* __restrict__ coords_h) {
    __shared__ __align__(16) float gseg[225 * 16];

    const int tid = threadIdx.x;
    const int l   = tid & 15;
    const int sid = blockIdx.x;
    const int p   = sid % PP;
    const int dir = (sid / PP) & 1;
    const int b   = sid / (2 * PP);
    const int base = SEG * (p + 1);
    const float* gb = grad + b * (HH * WW);

    {
        const int r  = tid >> 4;
        const int m  = tid & 15;
        const int sS = (dir == 0) ? WW : 1;
        const int sM = (dir == 0) ? 1  : WW;
        const float* src = gb + r * sS + (base - BW + m) * sM;
        const long stepBytes = (long)(4 * sS) * 4;
#pragma unroll 8
        for (int c = 0; c < 56; ++c) {
            __builtin_amdgcn_global_load_lds((gas_ptr)(const void*)src,
                                             (las_ptr)(void*)(&gseg[c * 64]), 4, 0, 0);
            src = (const float*)((const char*)src + stepBytes);
        }
    }
    __syncthreads();

    const float lane_add = (l < MM) ? 0.0f : __int_as_float(POS_INF_I);
    const float* gp = &gseg[l];

    unsigned wreg[16] = {};

#define DP_STEP(gval, ownb, jj_c)                                                       \
    {                                                                                   \
        float v1 = cost;                                                                \
        float v0 = __int_as_float(__builtin_amdgcn_update_dpp(                          \
            POS_INF_I, __float_as_int(cost), 0x111, 0xf, 0xf, false));                  \
        float v2 = __int_as_float(__builtin_amdgcn_update_dpp(                          \
            POS_INF_I, __float_as_int(cost), 0x101, 0xf, 0xf, false));                  \
        bool a01 = (v0 <= v1), a02 = (v0 <= v2), a12 = (v1 <= v2);                      \
        bool aa  = a01 && a02;                                                          \
        unsigned long long A   = __ballot(aa);                                          \
        unsigned long long C12 = __ballot(a12);                                         \
        unsigned long long B0 = ~A & C12;                                               \
        unsigned long long B1 = ~A & ~C12;                                              \
        float mv = aa ? v0 : (a12 ? v1 : v2);                                           \
        cost = mv - (gval) + lane_add;                                                  \
        unsigned wv = (unsigned)(B0 & 0x7FFull) | ((unsigned)(B1 & 0x7FFull) << 11);    \
        wreg[(jj_c)] = (ownb) ? wv : wreg[(jj_c)];                                      \
    }

    float cost = -gp[0] + lane_add;
    float buf[16], c0[16];
#pragma unroll
    for (int k = 0; k < 16; ++k) buf[k] = gp[(1 + k) * 16];
    for (int t = 0; t < 13; ++t) {
        const bool own = (tid == t);
#pragma unroll
        for (int k = 0; k < 16; ++k) c0[k] = buf[k];
#pragma unroll
        for (int k = 0; k < 16; ++k) buf[k] = gp[(16 * (t + 1) + 1 + k) * 16];
#pragma unroll
        for (int k = 0; k < 16; ++k) DP_STEP(c0[k], own, k)
    }
    {
        const bool own = (tid == 13);
#pragma unroll
        for (int k = 0; k < 15; ++k) DP_STEP(buf[k], own, k)
    }
#undef DP_STEP

    float bc = cost;
    int   bi = l;
#pragma unroll
    for (int mask = 1; mask < 16; mask <<= 1) {
        float oc = __shfl_xor(bc, mask, 16);
        int   oi = __shfl_xor(bi, mask, 16);
        if (oc < bc || (oc == bc && oi < bi)) { bc = oc; bi = oi; }
    }
    const int idx_last = bi;

    const int mcnt = (l < 13) ? 16 : ((l == 13) ? 15 : 0);
    const unsigned long long IDMAP = 0xA9876543210ull;
    unsigned long long L = IDMAP;
#pragma unroll
    for (int jj = 15; jj >= 0; --jj) {
        if (jj < mcnt) {
            unsigned ww = wreg[jj];
            unsigned long long M = 0ull;
#pragma unroll
            for (int i = 0; i < MM; ++i) {
                unsigned sel = ((ww >> i) & 1u) + 2u * ((ww >> (11 + i)) & 1u);
                M |= ((unsigned long long)(i + (int)sel - 1)) << (4 * i);
            }
            L = mcompose(M, L);
        }
    }
    unsigned long long I = L;
#pragma unroll
    for (int d = 1; d < 16; d <<= 1) {
        unsigned long long O = __shfl_down(I, d, 16);
        if (l + d < 16) I = mcompose(I, O);
    }
    unsigned long long R = __shfl_down(I, 1, 16);
    if (l == 15) R = IDMAP;

    int* cout = (dir == 0) ? coords_v : coords_h;
    if (tid == 15) cout[(b * HH + 223) * PP + p] = base + idx_last - BW;
    if (tid < 16) {
        unsigned v = (unsigned)(R >> (4 * idx_last)) & 15u;
#pragma unroll
        for (int jj = 15; jj >= 0; --jj) {
            if (jj < mcnt) {
                unsigned ww = wreg[jj];
                unsigned sel = ((ww >> v) & 1u) + 2u * ((ww >> (11 + v)) & 1u);
                v = v + sel - 1u;
                cout[(b * HH + (16 * l + jj)) * PP + p] = base + (int)v - BW;
            }
        }
    }
}

// ---------------------------------------------------------------------------
// labvote: initial labels (analytic, 38x14 LDS region) + vote iteration 1.
// R6-proven component. Grid (7,28,4) x (32,8).
// ---------------------------------------------------------------------------
#define RW 38
#define RH 14
#define RSTR 40

__global__ __launch_bounds__(256) void labvote_kernel(const int* __restrict__ cv,
                                                      const int* __restrict__ ch,
                                                      unsigned char* __restrict__ out8) {
    __shared__ unsigned char lab[RH * RSTR];
    __shared__ unsigned bins[16 * 256];
    const int tx = threadIdx.x, ty = threadIdx.y;
    const int t  = ty * 32 + tx;
    const int b  = blockIdx.z;
    const int GX0 = blockIdx.x * 32, GY0 = blockIdx.y * 8;

    for (int idx = t; idx < RW * RH; idx += 256) {
        int j = idx / RW, i = idx - j * RW;
        int gx = GX0 - 3 + i, gy = GY0 - 3 + j;
        if ((unsigned)gx < WW && (unsigned)gy < HH) {
            const int* cvp = cv + (b * HH + gy) * PP;
            const int* chp = ch + (b * WW + gx) * PP;
            int v = 0, h = 0;
#pragma unroll
            for (int q = 0; q < PP; ++q) { v += (cvp[q] <= gx); h += (chp[q] <= gy); }
            lab[j * RSTR + i] = (unsigned char)(v + 8 * h);
        }
    }
    __syncthreads();

    const int gx = GX0 + tx, gy = GY0 + ty;
#pragma unroll
    for (int c = 0; c < 16; ++c) bins[c * 256 + t] = 0u;
#pragma unroll
    for (int dy = -3; dy <= 3; ++dy) {
        if ((unsigned)(gy + dy) >= HH) continue;
#pragma unroll
        for (int dx = -3; dx <= 3; ++dx) {
            if ((unsigned)(gx + dx) >= WW) continue;
            int lb = lab[(ty + 3 + dy) * RSTR + (tx + 3 + dx)];
            int ay = dy < 0 ? -dy : dy, ax = dx < 0 ? -dx : dx;
            int d = ay > ax ? ay : ax;
            unsigned wgt = (d <= 1) ? 3u : (unsigned)(4 - d);
            atomicAdd(&bins[(lb >> 2) * 256 + t], wgt << ((lb & 3) * 8));
        }
    }
    int best_s = 0, best_k = 0;
#pragma unroll
    for (int c = 0; c < 16; ++c) {
        unsigned wd = bins[c * 256 + t];
        if (wd) {
#pragma unroll
            for (int q = 0; q < 4; ++q) {
                int s = (int)((wd >> (q * 8)) & 255u);
                if (s > best_s) { best_s = s; best_k = c * 4 + q; }
            }
        }
    }
    out8[(b * HH + gy) * WW + gx] = (unsigned char)best_k;
}

// ---------------------------------------------------------------------------
// vote kernel (byte-identical logic to R4's proven 2.4 us body)
// ---------------------------------------------------------------------------
__global__ __launch_bounds__(256) void vote_kernel(const unsigned char* __restrict__ in,
                                                   unsigned char* __restrict__ out8,
                                                   int* __restrict__ out32) {
    __shared__ unsigned bins[17 * 256];
    const int tx = threadIdx.x, ty = threadIdx.y;
    const int t  = ty * 32 + tx;
    const int x  = blockIdx.x * 32 + tx;
    const int y  = blockIdx.y * 8 + ty;
    const int b  = blockIdx.z;
    const unsigned char* img = in + b * (HH * WW);

#pragma unroll
    for (int c = 0; c < 17; ++c) bins[c * 256 + t] = 0u;

#pragma unroll
    for (int dy = -3; dy <= 3; ++dy) {
        int yy = y + dy;
        bool oky = (unsigned)yy < (unsigned)HH;
        int yc = min(max(yy, 0), HH - 1);
#pragma unroll
        for (int dx = -3; dx <= 3; ++dx) {
            int xx = x + dx;
            bool ok = oky && ((unsigned)xx < (unsigned)WW);
            int xc = min(max(xx, 0), WW - 1);
            int lab = img[yc * WW + xc];
            lab = ok ? lab : 64;
            const int ady = dy < 0 ? -dy : dy;
            const int adx = dx < 0 ? -dx : dx;
            const int d = ady > adx ? ady : adx;
            const unsigned wgt = (d <= 1) ? 3u : (unsigned)(4 - d);
            atomicAdd(&bins[(lab >> 2) * 256 + t], wgt << ((lab & 3) * 8));
        }
    }

    int best_s = -1, best_k = 0;
#pragma unroll
    for (int c = 0; c < 16; ++c) {
        unsigned wd = bins[c * 256 + t];
#pragma unroll
        for (int q = 0; q < 4; ++q) {
            int s = (int)((wd >> (q * 8)) & 255u);
            if (s > best_s) { best_s = s; best_k = c * 4 + q; }
        }
    }

    int o = b * (HH * WW) + y * WW + x;
    if (out8)  out8[o]  = (unsigned char)best_k;
    if (out32) out32[o] = best_k;
}

// ---------------------------------------------------------------------------
extern "C" void kernel_launch(void* const* d_in, const int* in_sizes, int n_in,
                              void* d_out, int out_size, void* d_ws, size_t ws_size,
                              hipStream_t stream) {
    const float* grad = (const float*)d_in[0];
    int* out = (int*)d_out;
    char* ws = (char*)d_ws;

    int* cv = (int*)(ws);                               // 25088 B
    int* ch = (int*)(ws + 25088);                       // 25088 B
    unsigned char* laW = (unsigned char*)(ws + 50176);  // ping (ws)
    unsigned char* laD = (unsigned char*)d_out;         // pong (inside d_out)

    dp_kernel<<<56, 64, 0, stream>>>(grad, cv, ch);

    dim3 grid(WW / 32, HH / 8, BB), blk(32, 8, 1);
    labvote_kernel<<<grid, blk, 0, stream>>>(cv, ch, laD);        // v1 -> laD
    vote_kernel<<<grid, blk, 0, stream>>>(laD, laW, nullptr);     // v2 -> laW
    vote_kernel<<<grid, blk, 0, stream>>>(laW, laD, nullptr);     // v3 -> laD
    vote_kernel<<<grid, blk, 0, stream>>>(laD, laW, nullptr);     // v4 -> laW
    vote_kernel<<<grid, blk, 0, stream>>>(laW, nullptr, out);     // v5 -> int out
}